// Round 1
// baseline (733.809 us; speedup 1.0000x reference)
//
#include <hip/hip_runtime.h>
#include <math.h>

#define NE 256
#define HD 4096
#define BM 32
#define BK 32
#define NG 8
#define TOPKG 4
#define TOPK 8

typedef __attribute__((address_space(1))) const void av1_void;
typedef __attribute__((address_space(3))) void av3_void;

__device__ __forceinline__ void g2l16(const void* g, void* l) {
  __builtin_amdgcn_global_load_lds((av1_void*)g, (av3_void*)l, 16, 0, 0);
}

// ---------------- W[e][k] -> Wt[k][e] ----------------
__global__ void wt_kernel(const float* __restrict__ W, float* __restrict__ Wt) {
  __shared__ float tile[32][33];
  int tx = threadIdx.x, ty = threadIdx.y;  // 32, 8
  int k0 = blockIdx.x * 32, e0 = blockIdx.y * 32;
#pragma unroll
  for (int r = 0; r < 4; ++r)
    tile[ty + 8 * r][tx] = W[(size_t)(e0 + ty + 8 * r) * HD + (k0 + tx)];
  __syncthreads();
#pragma unroll
  for (int r = 0; r < 4; ++r)
    Wt[(size_t)(k0 + ty + 8 * r) * NE + (e0 + tx)] = tile[tx][ty + 8 * r];
}

// ---------------- logits[t][e] = sum_k x[t][k] * Wt[k][e] ----------------
// fp32 FMA in 8-term micro-chunks, drained into fp64 accumulators for
// near-fp64 ranking fidelity at ~1.5x fp32 cost.
__global__ __launch_bounds__(256, 2) void logits_kernel(
    const float* __restrict__ X, const float* __restrict__ Wt,
    float* __restrict__ L, int T) {
  __shared__ __align__(16) float Ws[BK][NE];      // 32 KB, staged via global_load_lds
  __shared__ __align__(16) float Xs[BK][BM + 4];  // transposed x tile, padded

  int tid = threadIdx.x;
  int t0 = blockIdx.x * BM;
  int tx = tid & 31, ty = tid >> 5;
  int wave = tid >> 6, lane = tid & 63;
  int m = tid >> 3, kof = (tid & 7) * 4;

  float acc[4][8];
  double dacc[4][8];
#pragma unroll
  for (int i = 0; i < 4; ++i)
#pragma unroll
    for (int j = 0; j < 8; ++j) { acc[i][j] = 0.0f; dacc[i][j] = 0.0; }

  const float* xbase = X + (size_t)t0 * HD;
  char* wdst = (char*)&Ws[0][0];

  for (int kc = 0; kc < HD / BK; ++kc) {
    // stage W chunk (32 rows of Wt = contiguous 32 KB) -> LDS, linear dest
    const char* wsrc = (const char*)(Wt + (size_t)kc * BK * NE);
#pragma unroll
    for (int i = 0; i < 8; ++i) {
      int off = wave * 8192 + i * 1024;  // per-wave 1 KB per call
      g2l16(wsrc + off + lane * 16, wdst + off);
    }
    // stage x tile transposed: Xs[k][m]
    float4 xv = *(const float4*)(xbase + (size_t)m * HD + kc * BK + kof);
    Xs[kof + 0][m] = xv.x;
    Xs[kof + 1][m] = xv.y;
    Xs[kof + 2][m] = xv.z;
    Xs[kof + 3][m] = xv.w;
    __syncthreads();

    for (int k8 = 0; k8 < BK / 8; ++k8) {
#pragma unroll
      for (int kk = 0; kk < 8; ++kk) {
        int k = k8 * 8 + kk;
        float4 a  = *(const float4*)&Xs[k][ty * 4];
        float4 b0 = *(const float4*)&Ws[k][tx * 4];
        float4 b1 = *(const float4*)&Ws[k][tx * 4 + 128];
        float av[4] = {a.x, a.y, a.z, a.w};
        float bv[8] = {b0.x, b0.y, b0.z, b0.w, b1.x, b1.y, b1.z, b1.w};
#pragma unroll
        for (int i = 0; i < 4; ++i)
#pragma unroll
          for (int j = 0; j < 8; ++j)
            acc[i][j] = fmaf(av[i], bv[j], acc[i][j]);
      }
      // drain micro-chunk into fp64
#pragma unroll
      for (int i = 0; i < 4; ++i)
#pragma unroll
        for (int j = 0; j < 8; ++j) {
          dacc[i][j] += (double)acc[i][j];
          acc[i][j] = 0.0f;
        }
    }
    __syncthreads();
  }

#pragma unroll
  for (int i = 0; i < 4; ++i) {
    int t = t0 + ty * 4 + i;
#pragma unroll
    for (int j = 0; j < 8; ++j) {
      int e = (j < 4) ? (tx * 4 + j) : (128 + tx * 4 + (j - 4));
      L[(size_t)t * NE + e] = (float)dacc[i][j];
    }
  }
}

// ---------------- per-token gating: one block per token ----------------
__global__ __launch_bounds__(256) void topk_kernel(
    const float* __restrict__ L, const float* __restrict__ bias,
    float* __restrict__ out, int T) {
  int t = blockIdx.x;
  int e = threadIdx.x;
  __shared__ double sArr[NE];
  __shared__ double gsc[NG];
  __shared__ int gsel[NG];
  __shared__ double wv[4];
  __shared__ int wi[4];
  __shared__ int selIdx[TOPK];
  __shared__ double selS[TOPK];

  float lg = L[(size_t)t * NE + e];
  double s = 1.0 / (1.0 + exp(-(double)lg));  // fp64 sigmoid
  sArr[e] = s;
  double sc = s + (double)bias[e];

  // top-2 within each group of 32 consecutive experts (= 32-lane subgroup)
  double m1 = sc, m2 = -1e300;
#pragma unroll
  for (int off = 16; off >= 1; off >>= 1) {
    double o1 = __shfl_xor(m1, off, 32);
    double o2 = __shfl_xor(m2, off, 32);
    if (o1 > m1) { m2 = fmax(m1, o2); m1 = o1; }
    else          m2 = fmax(m2, o1);
  }
  if ((e & 31) == 0) gsc[e >> 5] = m1 + m2;
  __syncthreads();

  // top-4 groups, tie -> lower index (matches jax top_k stability)
  if (e == 0) {
    unsigned chosen = 0;
    for (int c = 0; c < TOPKG; ++c) {
      double best = -1e300; int bi = 0;
      for (int g = 0; g < NG; ++g)
        if (!((chosen >> g) & 1) && gsc[g] > best) { best = gsc[g]; bi = g; }
      chosen |= 1u << bi;
    }
    for (int g = 0; g < NG; ++g) gsel[g] = (chosen >> g) & 1;
  }
  __syncthreads();

  double msc = gsel[e >> 5] ? sc : -1e300;
  int mine = 0;
  for (int it = 0; it < TOPK; ++it) {
    double v = mine ? -1e301 : msc;
    int idx = e;
#pragma unroll
    for (int off = 32; off >= 1; off >>= 1) {
      double ov = __shfl_xor(v, off, 64);
      int oi = __shfl_xor(idx, off, 64);
      if (ov > v || (ov == v && oi < idx)) { v = ov; idx = oi; }
    }
    if ((e & 63) == 0) { wv[e >> 6] = v; wi[e >> 6] = idx; }
    __syncthreads();
    if (e == 0) {
      double bv = wv[0]; int bi = wi[0];
      for (int w = 1; w < 4; ++w)
        if (wv[w] > bv || (wv[w] == bv && wi[w] < bi)) { bv = wv[w]; bi = wi[w]; }
      selIdx[it] = bi; selS[it] = sArr[bi];
    }
    __syncthreads();
    if (e == selIdx[it]) mine = 1;
  }

  if (e < TOPK) {
    double denom = 1e-20;
#pragma unroll
    for (int j = 0; j < TOPK; ++j) denom += selS[j];
    out[(size_t)t * TOPK + e] = (float)selIdx[e];                       // output 0: idx
    out[(size_t)T * TOPK + (size_t)t * TOPK + e] =
        (float)(selS[e] / denom * 2.5);                                 // output 1: weight
  }
}

extern "C" void kernel_launch(void* const* d_in, const int* in_sizes, int n_in,
                              void* d_out, int out_size, void* d_ws, size_t ws_size,
                              hipStream_t stream) {
  const float* X    = (const float*)d_in[0];
  const float* W    = (const float*)d_in[1];
  const float* bias = (const float*)d_in[2];
  float* out = (float*)d_out;
  int T = in_sizes[0] / HD;  // 16384

  float* Wt = (float*)d_ws;                       // 4 MB
  float* L  = (float*)d_ws + (size_t)HD * NE;     // 16 MB

  wt_kernel<<<dim3(HD / 32, NE / 32), dim3(32, 8), 0, stream>>>(W, Wt);
  logits_kernel<<<T / BM, 256, 0, stream>>>(X, Wt, L, T);
  topk_kernel<<<T, 256, 0, stream>>>(L, bias, out, T);
}

// Round 2
// 377.705 us; speedup vs baseline: 1.9428x; 1.9428x over previous
//
#include <hip/hip_runtime.h>
#include <math.h>

#define NE 256
#define HD 4096
#define NG 8
#define TOPKG 4
#define TOPK 8

#define BM 128
#define BN 128
#define BK 32
#define NKB (HD / BK)  // 128

typedef __attribute__((ext_vector_type(8))) short short8;
typedef __attribute__((ext_vector_type(4))) float f32x4;

typedef __attribute__((address_space(1))) const void av1_void;
typedef __attribute__((address_space(3))) void av3_void;

__device__ __forceinline__ void g2l16(const void* g, void* l) {
  __builtin_amdgcn_global_load_lds((av1_void*)g, (av3_void*)l, 16, 0, 0);
}

#define MFMA __builtin_amdgcn_mfma_f32_16x16x32_bf16

// Read/write-side XOR swizzle: addr ^= ((row&7)<<4), row = addr>>6.
__device__ __forceinline__ unsigned swz(unsigned a) { return a ^ ((a >> 2) & 0x70u); }
// Inverse map (for global_load_lds source pre-swizzle): F(inv(d)) == d.
__device__ __forceinline__ unsigned inv_swz(unsigned d) {
  unsigned a = d ^ ((d >> 2) & 0x40u);
  a ^= ((a >> 2) & 0x30u);
  return a;
}

// Exact 3-way bf16 split by fp32-bit truncation: x = h + m + l + O(2^-24 x).
__device__ __forceinline__ void split3(float x, unsigned short& h, unsigned short& m,
                                       unsigned short& l) {
  unsigned bx = __float_as_uint(x);
  h = (unsigned short)(bx >> 16);
  float r = x - __uint_as_float(bx & 0xffff0000u);  // exact
  unsigned br = __float_as_uint(r);
  m = (unsigned short)(br >> 16);
  float r2 = r - __uint_as_float(br & 0xffff0000u);  // exact
  l = (unsigned short)(__float_as_uint(r2) >> 16);
}

// ---------------- W[e][k] f32 -> packed bf16 splits [kb][split][e][32] ----------------
__global__ void wsplit_kernel(const float* __restrict__ W, unsigned short* __restrict__ W3) {
  int kb = blockIdx.x;  // 0..127
  int e = threadIdx.x;  // 0..255
  const float* src = W + (size_t)e * HD + kb * BK;
#pragma unroll
  for (int g = 0; g < 4; ++g) {
    float4 x0 = *(const float4*)(src + g * 8);
    float4 x1 = *(const float4*)(src + g * 8 + 4);
    float xv[8] = {x0.x, x0.y, x0.z, x0.w, x1.x, x1.y, x1.z, x1.w};
    short8 hv, mv, lv;
#pragma unroll
    for (int j = 0; j < 8; ++j) {
      unsigned short h, m, l;
      split3(xv[j], h, m, l);
      hv[j] = (short)h; mv[j] = (short)m; lv[j] = (short)l;
    }
    size_t kbase = (size_t)kb * 3 * NE * 32;
    *(short8*)(W3 + kbase + 0 * NE * 32 + (size_t)e * 32 + g * 8) = hv;
    *(short8*)(W3 + kbase + 1 * NE * 32 + (size_t)e * 32 + g * 8) = mv;
    *(short8*)(W3 + kbase + 2 * NE * 32 + (size_t)e * 32 + g * 8) = lv;
  }
}

// ---------------- logits via split-bf16 MFMA ----------------
// Block: 128 tokens x 128 experts, 512 thr = 8 waves (2M x 4N), wave tile 64x32.
__global__ __launch_bounds__(512, 2) void logits_kernel(
    const float* __restrict__ X, const unsigned short* __restrict__ W3,
    float* __restrict__ L) {
  // per buf: A splits 3*8KB | B splits 3*8KB  => 48KB; double-buffered.
  __shared__ __align__(16) char lds[2][49152];

  const int tid = threadIdx.x;
  const int lane = tid & 63;
  const int wave = tid >> 6;
  const int wm = wave >> 2, wn = wave & 3;
  const int bm0 = blockIdx.x * BM;
  const int n0 = blockIdx.y * BN;

  // A staging: thread -> (row, 8-elem k segment)
  const int arow = tid >> 2;
  const int akseg = tid & 3;
  const unsigned awoff = swz((unsigned)(arow * 64 + akseg * 16));
  const float* xptr = X + (size_t)(bm0 + arow) * HD + akseg * 8;

  // B staging: linear dest tid*16 within each 8KB split region; pre-swizzled source.
  const unsigned bsoff = inv_swz((unsigned)(tid * 16));

  // fragment addresses
  const int afrow = wm * 64 + (lane & 15);  // + mi*16
  const int akg = lane >> 4;                // k-group
  const int bfcol = wn * 32 + (lane & 15);  // + ni*16

  f32x4 Chh[4][2], Cmid[4][2];
  double dacc[4][2][4];
#pragma unroll
  for (int mi = 0; mi < 4; ++mi)
#pragma unroll
    for (int ni = 0; ni < 2; ++ni) {
      Chh[mi][ni] = (f32x4)(0.0f);
      Cmid[mi][ni] = (f32x4)(0.0f);
#pragma unroll
      for (int j = 0; j < 4; ++j) dacc[mi][ni][j] = 0.0;
    }

  const char* wbase = (const char*)W3;

  auto stageB = [&](int kb, int buf) {
#pragma unroll
    for (int s = 0; s < 3; ++s) {
      size_t sb = (((size_t)kb * 3 + s) * 256 + n0) * 64;
      g2l16(wbase + sb + bsoff, &lds[buf][24576 + s * 8192 + tid * 16]);
    }
  };

  auto convertWriteA = [&](int buf, float4 xa, float4 xb) {
    float xv[8] = {xa.x, xa.y, xa.z, xa.w, xb.x, xb.y, xb.z, xb.w};
    short8 hv, mv, lv;
#pragma unroll
    for (int j = 0; j < 8; ++j) {
      unsigned short h, m, l;
      split3(xv[j], h, m, l);
      hv[j] = (short)h; mv[j] = (short)m; lv[j] = (short)l;
    }
    *(short8*)(&lds[buf][0 * 8192 + awoff]) = hv;
    *(short8*)(&lds[buf][1 * 8192 + awoff]) = mv;
    *(short8*)(&lds[buf][2 * 8192 + awoff]) = lv;
  };

  // ---- prologue: stage kb=0 ----
  {
    float4 xa = *(const float4*)(xptr);
    float4 xb = *(const float4*)(xptr + 4);
    stageB(0, 0);
    convertWriteA(0, xa, xb);
  }
  __syncthreads();

  for (int kb = 0; kb < NKB; ++kb) {
    const int buf = kb & 1;
    const bool more = (kb + 1 < NKB);
    float4 xa, xb;
    if (more) {
      xa = *(const float4*)(xptr + (size_t)(kb + 1) * BK);
      xb = *(const float4*)(xptr + (size_t)(kb + 1) * BK + 4);
      stageB(kb + 1, buf ^ 1);
    }

    // ---- compute on buf ----
    short8 af[4][3];
#pragma unroll
    for (int mi = 0; mi < 4; ++mi) {
      unsigned rbase = (unsigned)((afrow + mi * 16) * 64 + akg * 16);
#pragma unroll
      for (int s = 0; s < 3; ++s)
        af[mi][s] = *(const short8*)(&lds[buf][s * 8192 + swz(rbase)]);
    }
#pragma unroll
    for (int ni = 0; ni < 2; ++ni) {
      unsigned cbase = (unsigned)((bfcol + ni * 16) * 64 + akg * 16);
      short8 bh = *(const short8*)(&lds[buf][24576 + 0 * 8192 + swz(cbase)]);
      short8 bm_ = *(const short8*)(&lds[buf][24576 + 1 * 8192 + swz(cbase)]);
      short8 bl = *(const short8*)(&lds[buf][24576 + 2 * 8192 + swz(cbase)]);
#pragma unroll
      for (int mi = 0; mi < 4; ++mi) {
        Chh[mi][ni] = MFMA(af[mi][0], bh, Chh[mi][ni], 0, 0, 0);
        Cmid[mi][ni] = MFMA(af[mi][0], bm_, Cmid[mi][ni], 0, 0, 0);
        Cmid[mi][ni] = MFMA(af[mi][1], bh, Cmid[mi][ni], 0, 0, 0);
        Cmid[mi][ni] = MFMA(af[mi][1], bm_, Cmid[mi][ni], 0, 0, 0);
        Cmid[mi][ni] = MFMA(af[mi][0], bl, Cmid[mi][ni], 0, 0, 0);
        Cmid[mi][ni] = MFMA(af[mi][2], bh, Cmid[mi][ni], 0, 0, 0);
      }
    }

    if (more) convertWriteA(buf ^ 1, xa, xb);

    // drain hh chain to fp64 every 2 K-blocks (K=64)
    if (kb & 1) {
#pragma unroll
      for (int mi = 0; mi < 4; ++mi)
#pragma unroll
        for (int ni = 0; ni < 2; ++ni)
#pragma unroll
          for (int j = 0; j < 4; ++j) {
            dacc[mi][ni][j] += (double)Chh[mi][ni][j];
            Chh[mi][ni][j] = 0.0f;
          }
    }
    __syncthreads();
  }

  // ---- epilogue: C/D layout col=lane&15, row=(lane>>4)*4+j ----
#pragma unroll
  for (int mi = 0; mi < 4; ++mi)
#pragma unroll
    for (int ni = 0; ni < 2; ++ni) {
      int rowbase = bm0 + wm * 64 + mi * 16 + (lane >> 4) * 4;
      int col = n0 + wn * 32 + ni * 16 + (lane & 15);
#pragma unroll
      for (int j = 0; j < 4; ++j)
        L[(size_t)(rowbase + j) * NE + col] =
            (float)(dacc[mi][ni][j] + (double)Cmid[mi][ni][j]);
    }
}

// ---------------- per-token gating: one block per token (unchanged) ----------------
__global__ __launch_bounds__(256) void topk_kernel(
    const float* __restrict__ L, const float* __restrict__ bias,
    float* __restrict__ out, int T) {
  int t = blockIdx.x;
  int e = threadIdx.x;
  __shared__ double sArr[NE];
  __shared__ double gsc[NG];
  __shared__ int gsel[NG];
  __shared__ double wv[4];
  __shared__ int wi[4];
  __shared__ int selIdx[TOPK];
  __shared__ double selS[TOPK];

  float lg = L[(size_t)t * NE + e];
  double s = 1.0 / (1.0 + exp(-(double)lg));
  sArr[e] = s;
  double sc = s + (double)bias[e];

  double m1 = sc, m2 = -1e300;
#pragma unroll
  for (int off = 16; off >= 1; off >>= 1) {
    double o1 = __shfl_xor(m1, off, 32);
    double o2 = __shfl_xor(m2, off, 32);
    if (o1 > m1) { m2 = fmax(m1, o2); m1 = o1; }
    else          m2 = fmax(m2, o1);
  }
  if ((e & 31) == 0) gsc[e >> 5] = m1 + m2;
  __syncthreads();

  if (e == 0) {
    unsigned chosen = 0;
    for (int c = 0; c < TOPKG; ++c) {
      double best = -1e300; int bi = 0;
      for (int g = 0; g < NG; ++g)
        if (!((chosen >> g) & 1) && gsc[g] > best) { best = gsc[g]; bi = g; }
      chosen |= 1u << bi;
    }
    for (int g = 0; g < NG; ++g) gsel[g] = (chosen >> g) & 1;
  }
  __syncthreads();

  double msc = gsel[e >> 5] ? sc : -1e300;
  int mine = 0;
  for (int it = 0; it < TOPK; ++it) {
    double v = mine ? -1e301 : msc;
    int idx = e;
#pragma unroll
    for (int off = 32; off >= 1; off >>= 1) {
      double ov = __shfl_xor(v, off, 64);
      int oi = __shfl_xor(idx, off, 64);
      if (ov > v || (ov == v && oi < idx)) { v = ov; idx = oi; }
    }
    if ((e & 63) == 0) { wv[e >> 6] = v; wi[e >> 6] = idx; }
    __syncthreads();
    if (e == 0) {
      double bv = wv[0]; int bi = wi[0];
      for (int w = 1; w < 4; ++w)
        if (wv[w] > bv || (wv[w] == bv && wi[w] < bi)) { bv = wv[w]; bi = wi[w]; }
      selIdx[it] = bi; selS[it] = sArr[bi];
    }
    __syncthreads();
    if (e == selIdx[it]) mine = 1;
  }

  if (e < TOPK) {
    double denom = 1e-20;
#pragma unroll
    for (int j = 0; j < TOPK; ++j) denom += selS[j];
    out[(size_t)t * TOPK + e] = (float)selIdx[e];
    out[(size_t)T * TOPK + (size_t)t * TOPK + e] =
        (float)(selS[e] / denom * 2.5);
  }
}

extern "C" void kernel_launch(void* const* d_in, const int* in_sizes, int n_in,
                              void* d_out, int out_size, void* d_ws, size_t ws_size,
                              hipStream_t stream) {
  const float* X = (const float*)d_in[0];
  const float* W = (const float*)d_in[1];
  const float* bias = (const float*)d_in[2];
  float* out = (float*)d_out;
  int T = in_sizes[0] / HD;  // 16384

  unsigned short* W3 = (unsigned short*)d_ws;                       // 6 MB
  float* L = (float*)((char*)d_ws + (size_t)NKB * 3 * NE * 32 * 2); // 16 MB

  wsplit_kernel<<<NKB, 256, 0, stream>>>(W, W3);
  logits_kernel<<<dim3(T / BM, NE / BN), 512, 0, stream>>>(X, W3, L);
  topk_kernel<<<T, 256, 0, stream>>>(L, bias, out, T);
}